// Round 4
// baseline (377.487 us; speedup 1.0000x reference)
//
#include <hip/hip_runtime.h>

// HDCProcessor — three-pass formulation, no inter-block synchronization.
//   hdc[b,t,d] = s1*(0.7*s2*s3 + 0.3) in {±1.0, ∓0.4}; 0.3*s1 for t<2.
//   out[t] = U[t]*(1-DEC)/(1-DEC^{t+1}),  U[t] = DEC*U[t-1] + hdc[t].
// Pass A (states): per-chunk local scan end-states S -> g_S (8 MiB, L2-hot).
// Pass B (emit): each block folds its entering carry from g_S — truncated at
// HOPS=8 predecessors (weight 0.95^32 per hop; neglected term < 4e-7, vs
// 2e-3 measured absmax) — then seeded scan + normalize + nontemporal store.
// R1 post-mortem: cross-block lookback sync = 2.1 ms of fence stalls; never
// again. R2 post-mortem: dur_us ≈ harness-constant (~230 µs: 1-GiB re-poison
// fill + launch) + ~75 µs of kernels — so only kernel-side µs are winnable.
// R3: nontemporal builtin needs a NATIVE vector type (ext_vector_type), not
// HIP's float4 class — that was a compile error, logic unchanged.

#define VOCAB   256
#define D_      4096
#define T_      2048
#define B_      8
#define DEC     0.95f
#define CHUNK   32
#define NCH     (T_/CHUNK)        // 64
#define THREADS 128
#define DGRP    (D_/(THREADS*8))  // 4  (each thread owns 8 consecutive d's)
#define ROWB    (D_/8)            // 512 bytes per packed row
#define HOPS    8                 // carry fold depth (0.194^9 ~ 4e-7 rel)

typedef float f32x4 __attribute__((ext_vector_type(4)));

__device__ unsigned char g_P1[VOCAB*ROWB];
__device__ unsigned char g_P2[VOCAB*ROWB];  // signs shifted by 1 along D
__device__ unsigned char g_P3[VOCAB*ROWB];  // signs shifted by 2 along D
__device__ float g_invn[T_];                // (1-DEC)/(1-DEC^{t+1})
__device__ float g_S[B_*NCH*D_];            // local chunk end states (8 MiB)

__global__ __launch_bounds__(256) void pack_kernel(const float* __restrict__ cb) {
    int gid = blockIdx.x * 256 + threadIdx.x;     // 0 .. VOCAB*ROWB-1
    int r   = gid >> 9;
    int byt = gid & 511;
    const float* row = cb + r * D_;
    unsigned b1 = 0, b2 = 0, b3 = 0;
#pragma unroll
    for (int j = 0; j < 8; ++j) {
        int d = byt * 8 + j;
        unsigned s1 = __float_as_uint(row[d]) >> 31;
        unsigned s2 = __float_as_uint(row[(d - 1) & (D_ - 1)]) >> 31;
        unsigned s3 = __float_as_uint(row[(d - 2) & (D_ - 1)]) >> 31;
        b1 |= s1 << j; b2 |= s2 << j; b3 |= s3 << j;
    }
    g_P1[gid] = (unsigned char)b1;
    g_P2[gid] = (unsigned char)b2;
    g_P3[gid] = (unsigned char)b3;
    if (gid < T_)
        g_invn[gid] = (1.0f - DEC) / (1.0f - powf(DEC, (float)(gid + 1)));
}

// Per-(b,d)-step bind value: v = ±1.0 or ∓0.4 (or 0.3*s1 for t<2).
__device__ __forceinline__ void bind_step(unsigned ub1, unsigned n8,
                                          float magp, float magn, float* acc) {
#pragma unroll
    for (int j = 0; j < 8; ++j) {
        float mag    = ((n8 >> j) & 1u) ? magn : magp;
        unsigned sgn = (ub1 << (31 - j)) & 0x80000000u;
        float v      = __uint_as_float(__float_as_uint(mag) ^ sgn);
        acc[j] = fmaf(acc[j], DEC, v);
    }
}

__global__ __launch_bounds__(THREADS) void states_kernel(const int* __restrict__ idx) {
    const int b  = blockIdx.z;
    const int ch = blockIdx.y;
    const int dg = blockIdx.x;
    const int t0 = ch * CHUNK;
    const int lo = (t0 - 2 > 0) ? (t0 - 2) : 0;

    __shared__ int sidx[CHUNK + 2];
    if (threadIdx.x < (unsigned)(t0 + CHUNK - lo))
        sidx[threadIdx.x] = idx[b * T_ + lo + threadIdx.x];
    __syncthreads();

    const int i = dg * THREADS + threadIdx.x;
    float acc[8];
#pragma unroll
    for (int j = 0; j < 8; ++j) acc[j] = 0.0f;

#pragma unroll 4
    for (int k = 0; k < CHUNK; ++k) {
        int t = t0 + k;
        int r1 = sidx[t - lo];
        unsigned ub1 = g_P1[r1 * ROWB + i];
        unsigned n8 = 0; float magp = 1.0f, magn = -0.4f;
        if (t >= 2) {
            int r2 = sidx[t - 1 - lo], r3 = sidx[t - 2 - lo];
            n8 = (unsigned)(g_P2[r2 * ROWB + i] ^ g_P3[r3 * ROWB + i]);
        } else { magp = 0.3f; magn = 0.3f; }
        bind_step(ub1, n8, magp, magn, acc);
    }

    f32x4* S = (f32x4*)(g_S + (size_t)(b * NCH + ch) * D_ + (size_t)i * 8);
    S[0] = (f32x4){acc[0], acc[1], acc[2], acc[3]};
    S[1] = (f32x4){acc[4], acc[5], acc[6], acc[7]};
}

__global__ __launch_bounds__(THREADS) void emit_kernel(const int* __restrict__ idx,
                                                       float* __restrict__ out) {
    const int b  = blockIdx.z;
    const int ch = blockIdx.y;
    const int dg = blockIdx.x;
    const int t0 = ch * CHUNK;
    const int lo = (t0 - 2 > 0) ? (t0 - 2) : 0;

    __shared__ int   sidx[CHUNK + 2];
    __shared__ float sinv[CHUNK];
    if (threadIdx.x < (unsigned)(t0 + CHUNK - lo))
        sidx[threadIdx.x] = idx[b * T_ + lo + threadIdx.x];
    if (threadIdx.x < CHUNK)
        sinv[threadIdx.x] = g_invn[t0 + threadIdx.x];
    __syncthreads();

    const int i = dg * THREADS + threadIdx.x;

    // ---- entering carry: truncated fold over predecessor aggregates ----
    // c = sum_{p=ch-HOPS}^{ch-1} dch^{ch-1-p} * S[b,p,dslice], dch = DEC^32.
    float dch = DEC * DEC;            // DEC^32 by repeated squaring
    dch *= dch; dch *= dch; dch *= dch; dch *= dch;

    float c[8];
#pragma unroll
    for (int j = 0; j < 8; ++j) c[j] = 0.0f;
    {
        const int pend = (ch - HOPS > 0) ? (ch - HOPS) : 0;
        float w = 1.0f;
#pragma unroll 4
        for (int p = ch - 1; p >= pend; --p) {
            const f32x4* src = (const f32x4*)(g_S + (size_t)(b * NCH + p) * D_
                                              + (size_t)i * 8);
            f32x4 a0 = src[0];
            f32x4 a1 = src[1];
            c[0] = fmaf(w, a0.x, c[0]); c[1] = fmaf(w, a0.y, c[1]);
            c[2] = fmaf(w, a0.z, c[2]); c[3] = fmaf(w, a0.w, c[3]);
            c[4] = fmaf(w, a1.x, c[4]); c[5] = fmaf(w, a1.y, c[5]);
            c[6] = fmaf(w, a1.z, c[6]); c[7] = fmaf(w, a1.w, c[7]);
            w *= dch;
        }
    }

    // ---- seeded scan + normalize + nontemporal store ----
    float acc[8];
#pragma unroll
    for (int j = 0; j < 8; ++j) acc[j] = c[j];

    float* ob = out + (size_t)(b * T_) * D_ + (size_t)i * 8;
#pragma unroll 4
    for (int k = 0; k < CHUNK; ++k) {
        int t = t0 + k;
        int r1 = sidx[t - lo];
        unsigned ub1 = g_P1[r1 * ROWB + i];
        unsigned n8 = 0; float magp = 1.0f, magn = -0.4f;
        if (t >= 2) {
            int r2 = sidx[t - 1 - lo], r3 = sidx[t - 2 - lo];
            n8 = (unsigned)(g_P2[r2 * ROWB + i] ^ g_P3[r3 * ROWB + i]);
        } else { magp = 0.3f; magn = 0.3f; }
        bind_step(ub1, n8, magp, magn, acc);

        float invn = sinv[k];
        f32x4* o = (f32x4*)(ob + (size_t)t * D_);
        __builtin_nontemporal_store(
            (f32x4){acc[0]*invn, acc[1]*invn, acc[2]*invn, acc[3]*invn}, o);
        __builtin_nontemporal_store(
            (f32x4){acc[4]*invn, acc[5]*invn, acc[6]*invn, acc[7]*invn}, o + 1);
    }
}

extern "C" void kernel_launch(void* const* d_in, const int* in_sizes, int n_in,
                              void* d_out, int out_size, void* d_ws, size_t ws_size,
                              hipStream_t stream) {
    const float* cb  = (const float*)d_in[0];   // (256, 4096) fp32
    const int*   idx = (const int*)d_in[1];     // (8, 2048) int32
    float*       out = (float*)d_out;           // (8, 2048, 4096) fp32

    pack_kernel  <<<dim3((VOCAB * ROWB) / 256), dim3(256), 0, stream>>>(cb);
    states_kernel<<<dim3(DGRP, NCH, B_), dim3(THREADS), 0, stream>>>(idx);
    emit_kernel  <<<dim3(DGRP, NCH, B_), dim3(THREADS), 0, stream>>>(idx, out);
}

// Round 5
// 332.179 us; speedup vs baseline: 1.1364x; 1.1364x over previous
//
#include <hip/hip_runtime.h>

// HDCProcessor — two-dispatch formulation: pack + fused warm-up scan.
//   hdc[b,t,d] = s1*(0.7*s2*s3 + 0.3) in {±1.0, ∓0.4}; 0.3*s1 for t<2.
//   out[t] = U[t]*(1-DEC)/(1-DEC^{t+1}),  U[t] = DEC*U[t-1] + hdc[t].
// Each block owns (b, d-slice, 64-step segment). It re-runs the scan over the
// preceding WARM=256 raw steps (carry weight 0.95^256 ~ 2e-6 -> negligible;
// EXACT for t0<=256), then emits its 64 steps. No inter-block state, no g_S,
// no carry fold, no third dispatch.
// R1 post-mortem: cross-block lookback sync = 2.1 ms of fence stalls.
// R4 post-mortem: __builtin_nontemporal_store halved write BW (+73 µs) —
// plain dwordx4 stores already run at the 6.4 TB/s fill ceiling. Never nt.
// Model: dur_us ~ 230 µs harness constant (1-GiB re-poison fill ~167 + launch)
// + kernel time; only kernel-side µs are winnable.

#define VOCAB   256
#define D_      4096
#define T_      2048
#define B_      8
#define DEC     0.95f
#define SEG     64                 // output steps per block
#define NSEG    (T_/SEG)           // 32
#define WARM    256                // warm-up steps (0.95^256 ~ 2e-6 trunc err)
#define THREADS 128
#define DGRP    (D_/(THREADS*8))   // 4  (each thread owns 8 consecutive d's)
#define ROWB    (D_/8)             // 512 bytes per packed row
#define SIDXN   (WARM + SEG + 2)   // 322

typedef float f32x4 __attribute__((ext_vector_type(4)));

__device__ unsigned char g_P1[VOCAB*ROWB];
__device__ unsigned char g_P2[VOCAB*ROWB];  // signs shifted by 1 along D
__device__ unsigned char g_P3[VOCAB*ROWB];  // signs shifted by 2 along D
__device__ float g_invn[T_];                // (1-DEC)/(1-DEC^{t+1})

__global__ __launch_bounds__(256) void pack_kernel(const float* __restrict__ cb) {
    int gid = blockIdx.x * 256 + threadIdx.x;     // 0 .. VOCAB*ROWB-1
    int r   = gid >> 9;
    int byt = gid & 511;
    const float* row = cb + r * D_;
    unsigned b1 = 0, b2 = 0, b3 = 0;
#pragma unroll
    for (int j = 0; j < 8; ++j) {
        int d = byt * 8 + j;
        unsigned s1 = __float_as_uint(row[d]) >> 31;
        unsigned s2 = __float_as_uint(row[(d - 1) & (D_ - 1)]) >> 31;
        unsigned s3 = __float_as_uint(row[(d - 2) & (D_ - 1)]) >> 31;
        b1 |= s1 << j; b2 |= s2 << j; b3 |= s3 << j;
    }
    g_P1[gid] = (unsigned char)b1;
    g_P2[gid] = (unsigned char)b2;
    g_P3[gid] = (unsigned char)b3;
    if (gid < T_)
        g_invn[gid] = (1.0f - DEC) / (1.0f - powf(DEC, (float)(gid + 1)));
}

// Per-(b,d)-step bind value: v = ±1.0 or ∓0.4 (or 0.3*s1 for t<2).
__device__ __forceinline__ void bind_step(unsigned ub1, unsigned n8,
                                          float magp, float magn, float* acc) {
#pragma unroll
    for (int j = 0; j < 8; ++j) {
        float mag    = ((n8 >> j) & 1u) ? magn : magp;
        unsigned sgn = (ub1 << (31 - j)) & 0x80000000u;
        float v      = __uint_as_float(__float_as_uint(mag) ^ sgn);
        acc[j] = fmaf(acc[j], DEC, v);
    }
}

__global__ __launch_bounds__(THREADS) void fused_kernel(const int* __restrict__ idx,
                                                        float* __restrict__ out) {
    const int b  = blockIdx.z;
    const int s  = blockIdx.y;
    const int dg = blockIdx.x;
    const int t0 = s * SEG;
    const int t1 = t0 + SEG;
    const int tw = (t0 - WARM > 0) ? (t0 - WARM) : 0;   // warm-up start
    const int lo = (tw - 2 > 0) ? (tw - 2) : 0;
    const int n  = t1 - lo;                             // <= SIDXN

    __shared__ int   sidx[SIDXN];
    __shared__ float sinv[SEG];
    for (int k = threadIdx.x; k < n; k += THREADS)
        sidx[k] = idx[b * T_ + lo + k];
    if (threadIdx.x < SEG)
        sinv[threadIdx.x] = g_invn[t0 + threadIdx.x];
    __syncthreads();

    const int i = dg * THREADS + threadIdx.x;
    const unsigned char* __restrict__ P1 = g_P1 + i;
    const unsigned char* __restrict__ P2 = g_P2 + i;
    const unsigned char* __restrict__ P3 = g_P3 + i;

    float acc[8];
#pragma unroll
    for (int j = 0; j < 8; ++j) acc[j] = 0.0f;

    // ---- warm-up: scan only (no store). trip = min(t0, WARM), mult of 64 ----
#pragma unroll 4
    for (int t = tw; t < t0; ++t) {
        int r1 = sidx[t - lo];
        unsigned ub1 = P1[r1 * ROWB];
        unsigned n8 = 0; float magp = 1.0f, magn = -0.4f;
        if (t >= 2) {
            int r2 = sidx[t - 1 - lo], r3 = sidx[t - 2 - lo];
            n8 = (unsigned)(P2[r2 * ROWB] ^ P3[r3 * ROWB]);
        } else { magp = 0.3f; magn = 0.3f; }
        bind_step(ub1, n8, magp, magn, acc);
    }

    // ---- emit: seeded scan + normalize + store ----
    float* ob = out + (size_t)(b * T_) * D_ + (size_t)i * 8;
#pragma unroll 4
    for (int k = 0; k < SEG; ++k) {
        int t = t0 + k;
        int r1 = sidx[t - lo];
        unsigned ub1 = P1[r1 * ROWB];
        unsigned n8 = 0; float magp = 1.0f, magn = -0.4f;
        if (t >= 2) {
            int r2 = sidx[t - 1 - lo], r3 = sidx[t - 2 - lo];
            n8 = (unsigned)(P2[r2 * ROWB] ^ P3[r3 * ROWB]);
        } else { magp = 0.3f; magn = 0.3f; }
        bind_step(ub1, n8, magp, magn, acc);

        float invn = sinv[k];
        f32x4* o = (f32x4*)(ob + (size_t)t * D_);
        o[0] = (f32x4){acc[0]*invn, acc[1]*invn, acc[2]*invn, acc[3]*invn};
        o[1] = (f32x4){acc[4]*invn, acc[5]*invn, acc[6]*invn, acc[7]*invn};
    }
}

extern "C" void kernel_launch(void* const* d_in, const int* in_sizes, int n_in,
                              void* d_out, int out_size, void* d_ws, size_t ws_size,
                              hipStream_t stream) {
    const float* cb  = (const float*)d_in[0];   // (256, 4096) fp32
    const int*   idx = (const int*)d_in[1];     // (8, 2048) int32
    float*       out = (float*)d_out;           // (8, 2048, 4096) fp32

    pack_kernel <<<dim3((VOCAB * ROWB) / 256), dim3(256), 0, stream>>>(cb);
    fused_kernel<<<dim3(DGRP, NSEG, B_), dim3(THREADS), 0, stream>>>(idx, out);
}

// Round 6
// 294.285 us; speedup vs baseline: 1.2827x; 1.1288x over previous
//
#include <hip/hip_runtime.h>

// HDCProcessor — three-pass formulation, no inter-block synchronization.
//   hdc[b,t,d] = s1*(0.7*s2*s3 + 0.3) in {±1.0, ∓0.4}; 0.3*s1 for t<2.
//   out[t] = U[t]*(1-DEC)/(1-DEC^{t+1}),  U[t] = DEC*U[t-1] + hdc[t].
// Pass A (states): per-chunk local scan end-states S -> g_S (8 MiB, L2-hot).
// Pass B (emit): each block folds its entering carry from the HOPS=8 nearest
// predecessor aggregates (weight 0.95^32=0.194 per hop; neglected tail
// < 4e-7 vs the 2e-3 fp32-ordering absmax), then seeded scan + normalize +
// plain dwordx4 stores.
// Ledger: R1 cross-block lookback = 2.1 ms fence stalls (never). R4 nt-stores
// halved write BW (+73 µs; never). R5 warm-up fusion traded the 15 µs states
// pass for 25 µs of redundant VALU (+28; dispatch count is not the lever).
// Model: dur_us ~ 230 µs harness constant (re-poison fill ~165 + launch/sync)
// + kernel work (~70). Only kernel work is winnable; emit store ~42 µs floor.

#define VOCAB   256
#define D_      4096
#define T_      2048
#define B_      8
#define DEC     0.95f
#define CHUNK   32
#define NCH     (T_/CHUNK)        // 64
#define THREADS 128
#define DGRP    (D_/(THREADS*8))  // 4  (each thread owns 8 consecutive d's)
#define ROWB    (D_/8)            // 512 bytes per packed row
#define HOPS    8                 // carry fold depth (0.194^9/(1-0.194) ~ 4e-7)

typedef float f32x4 __attribute__((ext_vector_type(4)));

__device__ unsigned char g_P1[VOCAB*ROWB];
__device__ unsigned char g_P2[VOCAB*ROWB];  // signs shifted by 1 along D
__device__ unsigned char g_P3[VOCAB*ROWB];  // signs shifted by 2 along D
__device__ float g_invn[T_];                // (1-DEC)/(1-DEC^{t+1})
__device__ float g_S[B_*NCH*D_];            // local chunk end states (8 MiB)

__global__ __launch_bounds__(256) void pack_kernel(const float* __restrict__ cb) {
    int gid = blockIdx.x * 256 + threadIdx.x;     // 0 .. VOCAB*ROWB-1
    int r   = gid >> 9;
    int byt = gid & 511;
    const float* row = cb + r * D_;
    unsigned b1 = 0, b2 = 0, b3 = 0;
#pragma unroll
    for (int j = 0; j < 8; ++j) {
        int d = byt * 8 + j;
        unsigned s1 = __float_as_uint(row[d]) >> 31;
        unsigned s2 = __float_as_uint(row[(d - 1) & (D_ - 1)]) >> 31;
        unsigned s3 = __float_as_uint(row[(d - 2) & (D_ - 1)]) >> 31;
        b1 |= s1 << j; b2 |= s2 << j; b3 |= s3 << j;
    }
    g_P1[gid] = (unsigned char)b1;
    g_P2[gid] = (unsigned char)b2;
    g_P3[gid] = (unsigned char)b3;
    if (gid < T_)
        g_invn[gid] = (1.0f - DEC) / (1.0f - powf(DEC, (float)(gid + 1)));
}

// Per-(b,d)-step bind value: v = ±1.0 or ∓0.4 (or 0.3*s1 for t<2).
__device__ __forceinline__ void bind_step(unsigned ub1, unsigned n8,
                                          float magp, float magn, float* acc) {
#pragma unroll
    for (int j = 0; j < 8; ++j) {
        float mag    = ((n8 >> j) & 1u) ? magn : magp;
        unsigned sgn = (ub1 << (31 - j)) & 0x80000000u;
        float v      = __uint_as_float(__float_as_uint(mag) ^ sgn);
        acc[j] = fmaf(acc[j], DEC, v);
    }
}

__global__ __launch_bounds__(THREADS) void states_kernel(const int* __restrict__ idx) {
    const int b  = blockIdx.z;
    const int ch = blockIdx.y;            // 0 .. NCH-2 (last chunk never read)
    const int dg = blockIdx.x;
    const int t0 = ch * CHUNK;
    const int lo = (t0 - 2 > 0) ? (t0 - 2) : 0;

    __shared__ int sidx[CHUNK + 2];
    if (threadIdx.x < (unsigned)(t0 + CHUNK - lo))
        sidx[threadIdx.x] = idx[b * T_ + lo + threadIdx.x];
    __syncthreads();

    const int i = dg * THREADS + threadIdx.x;
    float acc[8];
#pragma unroll
    for (int j = 0; j < 8; ++j) acc[j] = 0.0f;

#pragma unroll 4
    for (int k = 0; k < CHUNK; ++k) {
        int t = t0 + k;
        int r1 = sidx[t - lo];
        unsigned ub1 = g_P1[r1 * ROWB + i];
        unsigned n8 = 0; float magp = 1.0f, magn = -0.4f;
        if (t >= 2) {
            int r2 = sidx[t - 1 - lo], r3 = sidx[t - 2 - lo];
            n8 = (unsigned)(g_P2[r2 * ROWB + i] ^ g_P3[r3 * ROWB + i]);
        } else { magp = 0.3f; magn = 0.3f; }
        bind_step(ub1, n8, magp, magn, acc);
    }

    f32x4* S = (f32x4*)(g_S + (size_t)(b * NCH + ch) * D_ + (size_t)i * 8);
    S[0] = (f32x4){acc[0], acc[1], acc[2], acc[3]};
    S[1] = (f32x4){acc[4], acc[5], acc[6], acc[7]};
}

__global__ __launch_bounds__(THREADS) void emit_kernel(const int* __restrict__ idx,
                                                       float* __restrict__ out) {
    const int b  = blockIdx.z;
    const int ch = blockIdx.y;
    const int dg = blockIdx.x;
    const int t0 = ch * CHUNK;
    const int lo = (t0 - 2 > 0) ? (t0 - 2) : 0;

    __shared__ int   sidx[CHUNK + 2];
    __shared__ float sinv[CHUNK];
    if (threadIdx.x < (unsigned)(t0 + CHUNK - lo))
        sidx[threadIdx.x] = idx[b * T_ + lo + threadIdx.x];
    if (threadIdx.x < CHUNK)
        sinv[threadIdx.x] = g_invn[t0 + threadIdx.x];
    __syncthreads();

    const int i = dg * THREADS + threadIdx.x;

    // ---- entering carry: truncated fold over predecessor aggregates ----
    // c = sum_{p=ch-HOPS}^{ch-1} dch^{ch-1-p} * S[b,p,dslice], dch = DEC^32.
    float dch = DEC * DEC;            // DEC^32 by repeated squaring
    dch *= dch; dch *= dch; dch *= dch; dch *= dch;

    float c[8];
#pragma unroll
    for (int j = 0; j < 8; ++j) c[j] = 0.0f;
    {
        const int pend = (ch - HOPS > 0) ? (ch - HOPS) : 0;
        float w = 1.0f;
#pragma unroll
        for (int p = ch - 1; p >= pend; --p) {
            const f32x4* src = (const f32x4*)(g_S + (size_t)(b * NCH + p) * D_
                                              + (size_t)i * 8);
            f32x4 a0 = src[0];
            f32x4 a1 = src[1];
            c[0] = fmaf(w, a0.x, c[0]); c[1] = fmaf(w, a0.y, c[1]);
            c[2] = fmaf(w, a0.z, c[2]); c[3] = fmaf(w, a0.w, c[3]);
            c[4] = fmaf(w, a1.x, c[4]); c[5] = fmaf(w, a1.y, c[5]);
            c[6] = fmaf(w, a1.z, c[6]); c[7] = fmaf(w, a1.w, c[7]);
            w *= dch;
        }
    }

    // ---- seeded scan + normalize + store (plain dwordx4) ----
    float acc[8];
#pragma unroll
    for (int j = 0; j < 8; ++j) acc[j] = c[j];

    float* ob = out + (size_t)(b * T_) * D_ + (size_t)i * 8;
#pragma unroll 4
    for (int k = 0; k < CHUNK; ++k) {
        int t = t0 + k;
        int r1 = sidx[t - lo];
        unsigned ub1 = g_P1[r1 * ROWB + i];
        unsigned n8 = 0; float magp = 1.0f, magn = -0.4f;
        if (t >= 2) {
            int r2 = sidx[t - 1 - lo], r3 = sidx[t - 2 - lo];
            n8 = (unsigned)(g_P2[r2 * ROWB + i] ^ g_P3[r3 * ROWB + i]);
        } else { magp = 0.3f; magn = 0.3f; }
        bind_step(ub1, n8, magp, magn, acc);

        float invn = sinv[k];
        f32x4* o = (f32x4*)(ob + (size_t)t * D_);
        o[0] = (f32x4){acc[0]*invn, acc[1]*invn, acc[2]*invn, acc[3]*invn};
        o[1] = (f32x4){acc[4]*invn, acc[5]*invn, acc[6]*invn, acc[7]*invn};
    }
}

extern "C" void kernel_launch(void* const* d_in, const int* in_sizes, int n_in,
                              void* d_out, int out_size, void* d_ws, size_t ws_size,
                              hipStream_t stream) {
    const float* cb  = (const float*)d_in[0];   // (256, 4096) fp32
    const int*   idx = (const int*)d_in[1];     // (8, 2048) int32
    float*       out = (float*)d_out;           // (8, 2048, 4096) fp32

    pack_kernel  <<<dim3((VOCAB * ROWB) / 256), dim3(256), 0, stream>>>(cb);
    states_kernel<<<dim3(DGRP, NCH - 1, B_), dim3(THREADS), 0, stream>>>(idx);
    emit_kernel  <<<dim3(DGRP, NCH, B_), dim3(THREADS), 0, stream>>>(idx, out);
}